// Round 7
// baseline (4544.370 us; speedup 1.0000x reference)
//
#include <hip/hip_runtime.h>
#include <hip/hip_bf16.h>

typedef __hip_bfloat16 bf16_t;

static const int cT  = 12;    // future steps
static const int cN  = 128;   // agents
static const int cH  = 128;   // hidden
static const int cK  = 20;    // modes
static const int cKN = 2560;  // cK*cN
static const int cS  = 4;     // batch split
static const int cNS = 32;    // agents per scene
static const int cL  = 640;   // cK*cNS attention length
static const int cHD = 32;    // head dim

#define CONV_TOTAL 977986

__constant__ int c_off[38] = {0,196608,212992,229376,229632,229888,557568,560128,562688,
  565248,630784,696320,696832,762368,827904,828416,844800,844928,861312,861440,877824,
  877952,910720,910976,943744,943872,960256,960384,960512,960640,960896,960960,977344,
  977472,977600,977728,977984,977986};
__constant__ int c_len[37] = {196608,16384,16384,256,256,327680,2560,2560,2560,
  65536,65536,512,65536,65536,512,16384,128,16384,128,16384,128,
  32768,256,32768,128,16384,128,128,128,256,2,16384,128,128,128,256,2};

struct Ptrs { const void* p[37]; };

__device__ __forceinline__ float sigm(float x){ return 1.f/(1.f+expf(-x)); }

// dtype sniffing + NaN canary
__global__ void k_detect(const unsigned short* ge_u16, int* flagp, unsigned int* outw){
  __shared__ int cnt;
  if (threadIdx.x == 0) cnt = 0;
  __syncthreads();
  int ok = 0;
  for (int i = threadIdx.x; i < 128; i += 64){
    unsigned short u = ge_u16[2*i];
    int ex = (u >> 7) & 0xFF;
    if (ex >= 100 && ex <= 140) ok++;
  }
  atomicAdd(&cnt, ok);
  __syncthreads();
  if (threadIdx.x == 0){
    *flagp = (cnt >= 96) ? 1 : 0;
    outw[0] = 0x7FC07FC0u;
  }
}

// convert all 37 inputs to fp32 into the conv region
__global__ void k_convert(Ptrs ptrs, const int* flagp, float* dst){
  int g = blockIdx.x*256 + threadIdx.x;
  if (g >= CONV_TOTAL) return;
  int flag = *flagp;
  int seg = 0;
  while (seg < 36 && g >= c_off[seg+1]) ++seg;
  int local = g - c_off[seg];
  if (local >= c_len[seg]) return;
  float v;
  if (flag) v = __bfloat162float(((const bf16_t*)ptrs.p[seg])[local]);
  else      v = ((const float*)ptrs.p[seg])[local];
  dst[g] = v;
}

// ge = relu(LN_2560(x @ mhp_W + b)), 2 rows per block, weight reuse across rows
__global__ void k_mhp(const float* x, const float* W, const float* b,
                      const float* g, const float* be, float* out){
  const int ROWS = 2;
  int r0 = blockIdx.x*ROWS;
  __shared__ float xs[ROWS][cH];
  __shared__ float red[256][3];
  int tid = threadIdx.x;
  if (tid < ROWS*32){
    int rr = tid>>5, u4 = tid&31;
    ((float4*)&xs[rr][0])[u4] = ((const float4*)x)[(r0+rr)*32 + u4];
  }
  __syncthreads();
  float y[ROWS][10];
  #pragma unroll
  for (int m = 0; m < 10; ++m){ float bb = b[tid + 256*m]; y[0][m] = bb; y[1][m] = bb; }
  for (int i = 0; i < cH; ++i){
    float x0 = xs[0][i], x1 = xs[1][i];
    const float* wr = W + i*2560 + tid;
    #pragma unroll
    for (int m = 0; m < 10; ++m){
      float w = wr[256*m];
      y[0][m] += x0*w; y[1][m] += x1*w;
    }
  }
  float ps0 = 0.f, ps1 = 0.f;
  #pragma unroll
  for (int m = 0; m < 10; ++m){ ps0 += y[0][m]; ps1 += y[1][m]; }
  red[tid][0] = ps0; red[tid][1] = ps1; __syncthreads();
  for (int s2 = 128; s2 > 0; s2 >>= 1){
    if (tid < s2){ red[tid][0] += red[tid+s2][0]; red[tid][1] += red[tid+s2][1]; }
    __syncthreads();
  }
  float mean0 = red[0][0]*(1.f/2560.f), mean1 = red[0][1]*(1.f/2560.f);
  __syncthreads();
  float pv0 = 0.f, pv1 = 0.f;
  #pragma unroll
  for (int m = 0; m < 10; ++m){
    float d0 = y[0][m]-mean0, d1 = y[1][m]-mean1;
    pv0 += d0*d0; pv1 += d1*d1;
  }
  red[tid][0] = pv0; red[tid][1] = pv1; __syncthreads();
  for (int s2 = 128; s2 > 0; s2 >>= 1){
    if (tid < s2){ red[tid][0] += red[tid+s2][0]; red[tid][1] += red[tid+s2][1]; }
    __syncthreads();
  }
  float inv0 = rsqrtf(red[0][0]*(1.f/2560.f) + 1e-5f);
  float inv1 = rsqrtf(red[0][1]*(1.f/2560.f) + 1e-5f);
  #pragma unroll
  for (int rr = 0; rr < ROWS; ++rr){
    int rg = r0 + rr;
    int t = rg >> 7, nn = rg & 127;
    float mean = rr ? mean1 : mean0;
    float inv  = rr ? inv1  : inv0;
    #pragma unroll
    for (int m = 0; m < 10; ++m){
      int col = tid + 256*m;
      float z = (y[rr][m]-mean)*inv*g[col] + be[col];
      z = fmaxf(z, 0.f);
      int k = col >> 7, hh2 = col & 127;
      out[((t*cKN) + k*cN + nn)*cH + hh2] = z;
    }
  }
}

// fused 12-step LSTM, 4 rows/block, h/c persistent in LDS; phase 2 adds soc/tanh.
__global__ void k_lstm_seq(const float* ge, float* outh,
    const float* hs0, const float* cn0, const float* soc,
    const float* Wih, const float* Whh, const float* bias, int phase){
  const int ROWS = 4;
  int r0 = blockIdx.x * ROWS;
  __shared__ float xs[ROWS][cH], hs[ROWS][cH], cs[ROWS][cH];
  int tid = threadIdx.x;
  if (tid < ROWS*32){
    int rr = tid>>5, u4 = tid&31;
    int nn = (r0+rr) & 127;
    ((float4*)&hs[rr][0])[u4] = ((const float4*)hs0)[nn*32 + u4];
    ((float4*)&cs[rr][0])[u4] = ((const float4*)cn0)[nn*32 + u4];
  }
  int u = tid & 127, half = tid >> 7;
  float b0 = bias[u], b1 = bias[128+u], b2 = bias[256+u], b3 = bias[384+u];
  for (int t = 0; t < cT; ++t){
    __syncthreads();   // orders previous step's hs/cs gate-writes vs this RMW
    if (tid < ROWS*32){
      int rr = tid>>5, u4 = tid&31;
      size_t gi4 = (size_t)t*cKN*32 + (size_t)(r0+rr)*32 + u4;
      ((float4*)&xs[rr][0])[u4] = ((const float4*)ge)[gi4];
      if (phase == 2){
        float4 sv = ((const float4*)soc)[gi4];
        float4 cv = ((float4*)&cs[rr][0])[u4];
        float4 hv = ((float4*)&hs[rr][0])[u4];
        cv.x += sv.x; cv.y += sv.y; cv.z += sv.z; cv.w += sv.w;
        hv.x += tanhf(cv.x); hv.y += tanhf(cv.y); hv.z += tanhf(cv.z); hv.w += tanhf(cv.w);
        ((float4*)&cs[rr][0])[u4] = cv;
        ((float4*)&hs[rr][0])[u4] = hv;
      }
    }
    __syncthreads();
    float a[2][4] = {{0.f,0.f,0.f,0.f},{0.f,0.f,0.f,0.f}};
    for (int i = 0; i < cH; ++i){
      const float* wr = Wih + i*512 + u;
      const float* vr = Whh + i*512 + u;
      float w0 = wr[0], w1 = wr[128], w2 = wr[256], w3 = wr[384];
      float v0 = vr[0], v1 = vr[128], v2 = vr[256], v3 = vr[384];
      #pragma unroll
      for (int q = 0; q < 2; ++q){
        int rr = half + 2*q;
        float xi = xs[rr][i], hi = hs[rr][i];
        a[q][0] += xi*w0 + hi*v0;
        a[q][1] += xi*w1 + hi*v1;
        a[q][2] += xi*w2 + hi*v2;
        a[q][3] += xi*w3 + hi*v3;
      }
    }
    __syncthreads();   // all dot reads of hs/cs done before overwrite
    #pragma unroll
    for (int q = 0; q < 2; ++q){
      int rr = half + 2*q;
      float ig = sigm(a[q][0]+b0), fg = sigm(a[q][1]+b1);
      float gg = tanhf(a[q][2]+b2), og = sigm(a[q][3]+b3);
      float c2 = fg*cs[rr][u] + ig*gg;
      float h2 = og*tanhf(c2);
      cs[rr][u] = c2; hs[rr][u] = h2;
      outh[(size_t)t*cKN*cH + (size_t)(r0+rr)*cH + u] = h2;
    }
  }
}

// loc & scale heads fused, 8 rows/block, weight reuse
__global__ void k_heads(const float* x,
  const float* lW1, const float* lb1, const float* lg, const float* lbe, const float* lW2, const float* lb2v,
  const float* sW1, const float* sb1, const float* sg, const float* sbe, const float* sW2, const float* sb2v,
  void* outv, int q0, float* locsc, const float* maxv, const float* svp, const int* flagp){
  const int ROWS = 8;
  int r0 = blockIdx.x*ROWS;
  __shared__ float xs[ROWS][cH];
  __shared__ float red[256][9];
  int tid = threadIdx.x;
  {
    int rr = tid>>5, u4 = tid&31;
    ((float4*)&xs[rr][0])[u4] = ((const float4*)x)[(size_t)(r0+rr)*32 + u4];
  }
  __syncthreads();
  int head = tid >> 7, j = tid & 127;
  const float* W1 = head ? sW1 : lW1;
  const float* b1 = head ? sb1 : lb1;
  const float* gv = head ? sg  : lg;
  const float* be = head ? sbe : lbe;
  const float* W2 = head ? sW2 : lW2;
  const float* b2 = head ? sb2v: lb2v;
  int base = head*128;
  float a[8];
  float bb = b1[j];
  #pragma unroll
  for (int r = 0; r < 8; ++r) a[r] = bb;
  for (int i = 0; i < cH; ++i){
    float w = W1[i*cH + j];
    #pragma unroll
    for (int r = 0; r < 8; ++r) a[r] += xs[r][i]*w;
  }
  #pragma unroll
  for (int r = 0; r < 8; ++r) red[tid][r] = a[r];
  __syncthreads();
  for (int s2 = 64; s2 > 0; s2 >>= 1){
    if ((tid&127) < s2){
      #pragma unroll
      for (int r = 0; r < 8; ++r) red[tid][r] += red[tid+s2][r];
    }
    __syncthreads();
  }
  float d[8];
  #pragma unroll
  for (int r = 0; r < 8; ++r) d[r] = a[r] - red[base][r]*(1.f/128.f);
  __syncthreads();
  #pragma unroll
  for (int r = 0; r < 8; ++r) red[tid][r] = d[r]*d[r];
  __syncthreads();
  for (int s2 = 64; s2 > 0; s2 >>= 1){
    if ((tid&127) < s2){
      #pragma unroll
      for (int r = 0; r < 8; ++r) red[tid][r] += red[tid+s2][r];
    }
    __syncthreads();
  }
  float z[8];
  float gj = gv[j], bej = be[j];
  #pragma unroll
  for (int r = 0; r < 8; ++r){
    float inv = rsqrtf(red[base][r]*(1.f/128.f) + 1e-5f);
    z[r] = fmaxf(d[r]*inv*gj + bej, 0.f);
  }
  __syncthreads();
  float w20 = W2[j*2+0], w21 = W2[j*2+1];
  #pragma unroll
  for (int r = 0; r < 8; ++r) red[tid][r] = z[r]*w20;
  __syncthreads();
  for (int s2 = 64; s2 > 0; s2 >>= 1){
    if ((tid&127) < s2){
      #pragma unroll
      for (int r = 0; r < 8; ++r) red[tid][r] += red[tid+s2][r];
    }
    __syncthreads();
  }
  float o0[8];
  #pragma unroll
  for (int r = 0; r < 8; ++r) o0[r] = red[base][r] + b2[0];
  __syncthreads();
  #pragma unroll
  for (int r = 0; r < 8; ++r) red[tid][r] = z[r]*w21;
  __syncthreads();
  for (int s2 = 64; s2 > 0; s2 >>= 1){
    if ((tid&127) < s2){
      #pragma unroll
      for (int r = 0; r < 8; ++r) red[tid][r] += red[tid+s2][r];
    }
    __syncthreads();
  }
  if (j == 0){
    int flag = *flagp;
    for (int r = 0; r < 8; ++r){
      float v0 = o0[r];
      float v1 = red[base][r] + b2[1];
      int rg = r0 + r;
      int t = rg / cKN, rem = rg - t*cKN;
      int k = rem >> 7, nn = rem & 127;
      if (head == 0){
        size_t oi = (((size_t)q0*cK + k)*cN + nn)*(cT*2) + t*2;
        if (flag){ ((bf16_t*)outv)[oi] = __float2bfloat16(v0); ((bf16_t*)outv)[oi+1] = __float2bfloat16(v1); }
        else     { ((float*)outv)[oi] = v0; ((float*)outv)[oi+1] = v1; }
        if (locsc){
          locsc[((size_t)t*cKN + rem)*2 + 0] = v0*maxv[nn*2+0] + svp[nn*2+0];
          locsc[((size_t)t*cKN + rem)*2 + 1] = v1*maxv[nn*2+1] + svp[nn*2+1];
        }
      } else {
        float e0 = (v0 > 0.f ? v0 : expm1f(v0)) + 1.001f;
        float e1 = (v1 > 0.f ? v1 : expm1f(v1)) + 1.001f;
        size_t oi = (((size_t)(q0+1)*cK + k)*cN + nn)*(cT*2) + t*2;
        if (flag){ ((bf16_t*)outv)[oi] = __float2bfloat16(e0); ((bf16_t*)outv)[oi+1] = __float2bfloat16(e1); }
        else     { ((float*)outv)[oi] = e0; ((float*)outv)[oi+1] = e1; }
      }
    }
  }
}

__global__ void k_mask(const float* locsc, unsigned char* m){
  int st = blockIdx.x;
  int s = st / cT, t = st - s*cT;
  __shared__ float lx[cK][cNS], ly[cK][cNS];
  int tid = threadIdx.x;
  for (int p = tid; p < cK*cNS; p += 256){
    int k = p >> 5, i = p & 31;
    int row = t*cKN + k*cN + s*cNS + i;
    lx[k][i] = locsc[row*2+0];
    ly[k][i] = locsc[row*2+1];
  }
  __syncthreads();
  for (int p = tid; p < 1024; p += 256){
    int i = p >> 5, j = p & 31;
    bool any = false;
    for (int k = 0; k < cK; ++k){
      float dx = fabsf(lx[k][i]-lx[k][j]);
      float dy = fabsf(ly[k][i]-ly[k][j]);
      any = any || ((dx < 10.f) && (dy < 10.f));
    }
    m[st*1024 + p] = any ? 1 : 0;
  }
}

// QKV projection, 16 rows/block, weight reuse for 8 rows/thread
__global__ void k_qkv(const float* x,
  const float* Wq, const float* bq, const float* Wk, const float* bk,
  const float* Wv, const float* bv,
  float* Q, float* K2, float* V){
  const int ROWS = 16;
  int r0 = blockIdx.x*ROWS;
  __shared__ float xs[ROWS][cH];
  int tid = threadIdx.x;
  for (int p = tid; p < ROWS*32; p += 256){
    int rr = p>>5, u4 = p&31;
    ((float4*)&xs[rr][0])[u4] = ((const float4*)x)[(size_t)(r0+rr)*32 + u4];
  }
  __syncthreads();
  int cl = tid & 127, half = tid >> 7;
  float aq[8], ak[8], av[8];
  float bq0 = bq[cl], bk0 = bk[cl], bv0 = bv[cl];
  #pragma unroll
  for (int r = 0; r < 8; ++r){ aq[r] = bq0; ak[r] = bk0; av[r] = bv0; }
  for (int i = 0; i < cH; ++i){
    float wq = Wq[i*cH+cl], wk = Wk[i*cH+cl], wv = Wv[i*cH+cl];
    #pragma unroll
    for (int q2 = 0; q2 < 8; ++q2){
      float xi = xs[half + 2*q2][i];
      aq[q2] += xi*wq; ak[q2] += xi*wk; av[q2] += xi*wv;
    }
  }
  #pragma unroll
  for (int q2 = 0; q2 < 8; ++q2){
    size_t gi = (size_t)(r0 + half + 2*q2)*cH + cl;
    Q[gi] = aq[q2]; K2[gi] = ak[q2]; V[gi] = av[q2];
  }
}

// flash-style masked MHSA v3: 64 q-rows/block, 4x4 register tiling (QK) and
// 4x2 (PV), Q staged once in LDS, bitmask masks in registers, online softmax,
// double-buffered K/V staging, 2 barriers per 64-key tile.
__global__ void k_attn(const float* Q, const float* Kx, const float* V,
                       const unsigned char* msk, float* ctx){
  int tile = blockIdx.x;        // 0..9 (64 q-rows each)
  int head = blockIdx.y;        // 0..3
  int st   = blockIdx.z;        // s*cT + t
  int s = st / cT, t = st - s*cT;
  __shared__ float Qs[64][36];           // 9216 B
  __shared__ float Kb[2][64][36];        // 18432 B
  __shared__ float Vt[2][32][68];        // 17408 B (V transposed per tile)
  __shared__ float Pb[64][68];           // 17408 B
  __shared__ unsigned int ml32[32];      // 128 B   (total 62592 B)
  int tid = threadIdx.x;
  int i = tid >> 4, j = tid & 15;
  int l0 = tile*64;
  // build per-agent mask bitmasks
  if (tid < 32){
    unsigned int m = 0;
    const unsigned char* mr = msk + st*1024 + tid*32;
    #pragma unroll
    for (int jj = 0; jj < 32; ++jj) m |= (mr[jj] ? 1u : 0u) << jj;
    ml32[tid] = m;
  }
  int kk_a = tid >> 3, f4_a = tid & 7;   // staging slots: rows kk_a, kk_a+32
  // stage Q (64 rows x 32 dims)
  {
    int l = l0 + kk_a;
    int grow = t*cKN + (l>>5)*cN + s*cNS + (l&31);
    ((float4*)&Qs[kk_a][0])[f4_a] = ((const float4*)Q)[(size_t)grow*32 + head*8 + f4_a];
    l = l0 + kk_a + 32;
    grow = t*cKN + (l>>5)*cN + s*cNS + (l&31);
    ((float4*)&Qs[kk_a+32][0])[f4_a] = ((const float4*)Q)[(size_t)grow*32 + head*8 + f4_a];
  }
  const float scl = 0.17677669529663687f;   // 1/sqrt(32)

  #define KADDR(c0,kk,f4) ((const float4*)Kx + (size_t)(t*cKN + (((c0)+(kk))>>5)*cN + s*cNS + (((c0)+(kk))&31))*32 + head*8 + (f4))
  #define VADDR(c0,kk,f4) ((const float4*)V  + (size_t)(t*cKN + (((c0)+(kk))>>5)*cN + s*cNS + (((c0)+(kk))&31))*32 + head*8 + (f4))

  float4 kpre0 = *KADDR(0, kk_a, f4_a);
  float4 kpre1 = *KADDR(0, kk_a+32, f4_a);
  float4 vpre0 = *VADDR(0, kk_a, f4_a);
  float4 vpre1 = *VADDR(0, kk_a+32, f4_a);
  {
    ((float4*)&Kb[0][kk_a][0])[f4_a] = kpre0;
    ((float4*)&Kb[0][kk_a+32][0])[f4_a] = kpre1;
    int d0 = f4_a*4;
    Vt[0][d0+0][kk_a] = vpre0.x; Vt[0][d0+1][kk_a] = vpre0.y;
    Vt[0][d0+2][kk_a] = vpre0.z; Vt[0][d0+3][kk_a] = vpre0.w;
    Vt[0][d0+0][kk_a+32] = vpre1.x; Vt[0][d0+1][kk_a+32] = vpre1.y;
    Vt[0][d0+2][kk_a+32] = vpre1.z; Vt[0][d0+3][kk_a+32] = vpre1.w;
  }
  __syncthreads();

  // per-thread row masks: rows 4i..4i+3, key-agent nibble (4j..4j+3)
  unsigned int nib[4];
  #pragma unroll
  for (int r = 0; r < 4; ++r){
    unsigned int mrow = ml32[(4*i + r) & 31];
    nib[r] = (mrow >> ((4*j) & 31)) & 0xFu;
  }
  float m_run[4] = {-3.4e38f,-3.4e38f,-3.4e38f,-3.4e38f};
  float l_run[4] = {0.f,0.f,0.f,0.f};
  float O[4][2] = {{0.f,0.f},{0.f,0.f},{0.f,0.f},{0.f,0.f}};

  for (int c = 0; c < 10; ++c){
    int par = c & 1;
    if (c < 9){
      int c1 = (c+1)*64;
      kpre0 = *KADDR(c1, kk_a, f4_a);
      kpre1 = *KADDR(c1, kk_a+32, f4_a);
      vpre0 = *VADDR(c1, kk_a, f4_a);
      vpre1 = *VADDR(c1, kk_a+32, f4_a);
    }
    // QK: 4 rows x 4 keys per thread
    float sc[4][4] = {{0,0,0,0},{0,0,0,0},{0,0,0,0},{0,0,0,0}};
    #pragma unroll
    for (int ch = 0; ch < 8; ++ch){
      float4 q0 = ((const float4*)&Qs[4*i+0][0])[ch];
      float4 q1 = ((const float4*)&Qs[4*i+1][0])[ch];
      float4 q2 = ((const float4*)&Qs[4*i+2][0])[ch];
      float4 q3 = ((const float4*)&Qs[4*i+3][0])[ch];
      #pragma unroll
      for (int kk = 0; kk < 4; ++kk){
        float4 kv = ((const float4*)&Kb[par][4*j+kk][0])[ch];
        sc[0][kk] += q0.x*kv.x + q0.y*kv.y + q0.z*kv.z + q0.w*kv.w;
        sc[1][kk] += q1.x*kv.x + q1.y*kv.y + q1.z*kv.z + q1.w*kv.w;
        sc[2][kk] += q2.x*kv.x + q2.y*kv.y + q2.z*kv.z + q2.w*kv.w;
        sc[3][kk] += q3.x*kv.x + q3.y*kv.y + q3.z*kv.z + q3.w*kv.w;
      }
    }
    // online softmax per row
    #pragma unroll
    for (int r = 0; r < 4; ++r){
      float sv[4];
      #pragma unroll
      for (int kk = 0; kk < 4; ++kk)
        sv[kk] = ((nib[r] >> kk) & 1u) ? sc[r][kk]*scl : -3.4e38f;
      float tmax = fmaxf(fmaxf(sv[0],sv[1]), fmaxf(sv[2],sv[3]));
      #pragma unroll
      for (int off = 1; off < 16; off <<= 1)
        tmax = fmaxf(tmax, __shfl_xor(tmax, off, 16));
      float m_new = fmaxf(m_run[r], tmax);
      float alpha = expf(m_run[r] - m_new);
      float p[4], psum = 0.f;
      #pragma unroll
      for (int kk = 0; kk < 4; ++kk){
        p[kk] = ((nib[r] >> kk) & 1u) ? expf(sv[kk] - m_new) : 0.f;
        psum += p[kk];
      }
      #pragma unroll
      for (int off = 1; off < 16; off <<= 1)
        psum += __shfl_xor(psum, off, 16);
      l_run[r] = l_run[r]*alpha + psum;
      m_run[r] = m_new;
      O[r][0] *= alpha; O[r][1] *= alpha;
      float4 p4; p4.x = p[0]; p4.y = p[1]; p4.z = p[2]; p4.w = p[3];
      ((float4*)&Pb[4*i+r][0])[j] = p4;
    }
    __syncthreads();   // Pb visible; Kb[par] reads done
    // PV: rows 4i..4i+3 x dims 2j, 2j+1
    #pragma unroll
    for (int m = 0; m < 16; ++m){
      float4 v0 = ((const float4*)&Vt[par][2*j+0][0])[m];
      float4 v1 = ((const float4*)&Vt[par][2*j+1][0])[m];
      #pragma unroll
      for (int r = 0; r < 4; ++r){
        float4 pv = ((const float4*)&Pb[4*i+r][0])[m];
        O[r][0] += pv.x*v0.x + pv.y*v0.y + pv.z*v0.z + pv.w*v0.w;
        O[r][1] += pv.x*v1.x + pv.y*v1.y + pv.z*v1.z + pv.w*v1.w;
      }
    }
    if (c < 9){
      int nb = 1 - par;
      ((float4*)&Kb[nb][kk_a][0])[f4_a] = kpre0;
      ((float4*)&Kb[nb][kk_a+32][0])[f4_a] = kpre1;
      int d0 = f4_a*4;
      Vt[nb][d0+0][kk_a] = vpre0.x; Vt[nb][d0+1][kk_a] = vpre0.y;
      Vt[nb][d0+2][kk_a] = vpre0.z; Vt[nb][d0+3][kk_a] = vpre0.w;
      Vt[nb][d0+0][kk_a+32] = vpre1.x; Vt[nb][d0+1][kk_a+32] = vpre1.y;
      Vt[nb][d0+2][kk_a+32] = vpre1.z; Vt[nb][d0+3][kk_a+32] = vpre1.w;
    }
    __syncthreads();   // PV reads of Pb/Vt done; staging writes done
  }
  #undef KADDR
  #undef VADDR
  #pragma unroll
  for (int r = 0; r < 4; ++r){
    float rinv = 1.f / l_run[r];
    int l = l0 + 4*i + r;
    int grow = t*cKN + (l>>5)*cN + s*cNS + (l&31);
    float2 o2; o2.x = O[r][0]*rinv; o2.y = O[r][1]*rinv;
    ((float2*)(ctx + (size_t)grow*cH + head*cHD))[j] = o2;
  }
}

// Wo1 + relu, 8 rows/block, weight reuse
__global__ void k_wo1(const float* x, const float* W, const float* b, float* o){
  const int ROWS = 8;
  int r0 = blockIdx.x*ROWS;
  __shared__ float xs[ROWS][cH];
  int tid = threadIdx.x;
  {
    int rr = tid>>5, u4 = tid&31;
    ((float4*)&xs[rr][0])[u4] = ((const float4*)x)[(size_t)(r0+rr)*32 + u4];
  }
  __syncthreads();
  float a[8];
  float bb = b[tid];
  #pragma unroll
  for (int r = 0; r < 8; ++r) a[r] = bb;
  for (int i = 0; i < cH; ++i){
    float w = W[i*256 + tid];
    #pragma unroll
    for (int r = 0; r < 8; ++r) a[r] += xs[r][i]*w;
  }
  #pragma unroll
  for (int r = 0; r < 8; ++r) o[(size_t)(r0+r)*256 + tid] = fmaxf(a[r], 0.f);
}

// Wo2, 16 rows/block, weight reuse
__global__ void k_wo2(const float* x, const float* W, const float* b, float* o){
  const int ROWS = 16;
  int r0 = blockIdx.x*ROWS;
  __shared__ float xs[ROWS][256];
  int tid = threadIdx.x;
  for (int p = tid; p < ROWS*64; p += 256){
    int rr = p>>6, u4 = p&63;
    ((float4*)&xs[rr][0])[u4] = ((const float4*)x)[(size_t)(r0+rr)*64 + u4];
  }
  __syncthreads();
  int cl = tid & 127, half = tid >> 7;
  float a[8];
  float bb = b[cl];
  #pragma unroll
  for (int r = 0; r < 8; ++r) a[r] = bb;
  for (int i = 0; i < 256; ++i){
    float w = W[i*cH + cl];
    #pragma unroll
    for (int q2 = 0; q2 < 8; ++q2) a[q2] += xs[half + 2*q2][i]*w;
  }
  #pragma unroll
  for (int q2 = 0; q2 < 8; ++q2) o[(size_t)(r0 + half + 2*q2)*cH + cl] = a[q2];
}

extern "C" void kernel_launch(void* const* d_in, const int* in_sizes, int n_in,
                              void* d_out, int out_size, void* d_ws, size_t ws_size,
                              hipStream_t stream){
  (void)in_sizes; (void)n_in; (void)out_size; (void)ws_size;

  int*   flagp = (int*)d_ws;
  float* conv  = (float*)d_ws + 64;
  float* big   = (float*)d_ws + 978112;

  const float* ge_f   = conv + 0;
  const float* hs_f   = conv + 196608;
  const float* cn_f   = conv + 212992;
  const float* sv_f   = conv + 229376;
  const float* mx_f   = conv + 229632;
  const float* mhpW_f = conv + 229888;
  const float* mhpb_f = conv + 557568;
  const float* mhpg_f = conv + 560128;
  const float* mhpbe_f= conv + 562688;
  const float* l1Wih_f= conv + 565248;
  const float* l1Whh_f= conv + 630784;
  const float* l1b_f  = conv + 696320;
  const float* l2Wih_f= conv + 696832;
  const float* l2Whh_f= conv + 762368;
  const float* l2b_f  = conv + 827904;
  const float* Wq_f   = conv + 828416;
  const float* bq_f   = conv + 844800;
  const float* Wk_f   = conv + 844928;
  const float* bk_f   = conv + 861312;
  const float* Wv_f   = conv + 861440;
  const float* bv_f   = conv + 877824;
  const float* Wo1_f  = conv + 877952;
  const float* bo1_f  = conv + 910720;
  const float* Wo2_f  = conv + 910976;
  const float* bo2_f  = conv + 943744;
  const float* locW1_f= conv + 943872;
  const float* locb1_f= conv + 960256;
  const float* locg_f = conv + 960384;
  const float* locbe_f= conv + 960512;
  const float* locW2_f= conv + 960640;
  const float* locb2_f= conv + 960896;
  const float* sclW1_f= conv + 960960;
  const float* sclb1_f= conv + 977344;
  const float* sclg_f = conv + 977472;
  const float* sclbe_f= conv + 977600;
  const float* sclW2_f= conv + 977728;
  const float* sclb2_f= conv + 977984;

  const size_t SLOT = (size_t)cT*cKN*cH;
  float* geb = big;
  float* o1b = big + SLOT;
  float* Qb  = big + 2*SLOT;
  float* Kb  = big + 3*SLOT;
  float* Vb  = big + 4*SLOT;
  float* locsc = big + 5*SLOT;
  unsigned char* maskb = (unsigned char*)(locsc + (size_t)cT*cKN*2);
  float* t1 = Qb;        // spans slots 2-3 (Q/K dead after attn)
  float* social = Vb;    // overlays V after attention

  Ptrs ptrs;
  for (int i = 0; i < 37; ++i) ptrs.p[i] = d_in[i];

  k_detect<<<1, 64, 0, stream>>>((const unsigned short*)d_in[0], flagp, (unsigned int*)d_out);
  k_convert<<<(CONV_TOTAL+255)/256, 256, 0, stream>>>(ptrs, flagp, conv);
  k_mhp<<<cT*cN/2, 256, 0, stream>>>(ge_f, mhpW_f, mhpb_f, mhpg_f, mhpbe_f, geb);
  k_lstm_seq<<<cKN/4, 256, 0, stream>>>(geb, o1b, hs_f, cn_f, (const float*)0,
                                        l1Wih_f, l1Whh_f, l1b_f, 1);
  k_heads<<<cT*cKN/8, 256, 0, stream>>>(o1b, locW1_f,locb1_f,locg_f,locbe_f,locW2_f,locb2_f,
                                        sclW1_f,sclb1_f,sclg_f,sclbe_f,sclW2_f,sclb2_f,
                                        d_out, 0, locsc, mx_f, sv_f, flagp);
  k_mask<<<cS*cT, 256, 0, stream>>>(locsc, maskb);
  k_qkv<<<cT*cKN/16, 256, 0, stream>>>(o1b, Wq_f,bq_f, Wk_f,bk_f, Wv_f,bv_f, Qb, Kb, Vb);
  {
    dim3 ag(cL/64, 4, cS*cT);
    k_attn<<<ag, 256, 0, stream>>>(Qb, Kb, Vb, maskb, o1b);   // ctx overlays out1
  }
  k_wo1<<<cT*cKN/8, 256, 0, stream>>>(o1b, Wo1_f, bo1_f, t1);
  k_wo2<<<cT*cKN/16, 256, 0, stream>>>(t1, Wo2_f, bo2_f, social);
  k_lstm_seq<<<cKN/4, 256, 0, stream>>>(geb, o1b, hs_f, cn_f, social,
                                        l2Wih_f, l2Whh_f, l2b_f, 2);
  k_heads<<<cT*cKN/8, 256, 0, stream>>>(o1b, locW1_f,locb1_f,locg_f,locbe_f,locW2_f,locb2_f,
                                        sclW1_f,sclb1_f,sclg_f,sclbe_f,sclW2_f,sclb2_f,
                                        d_out, 2, (float*)0, mx_f, sv_f, flagp);
}

// Round 8
// 1700.464 us; speedup vs baseline: 2.6724x; 2.6724x over previous
//
#include <hip/hip_runtime.h>
#include <hip/hip_bf16.h>

typedef __hip_bfloat16 bf16_t;

static const int cT  = 12;    // future steps
static const int cN  = 128;   // agents
static const int cH  = 128;   // hidden
static const int cK  = 20;    // modes
static const int cKN = 2560;  // cK*cN
static const int cS  = 4;     // batch split
static const int cNS = 32;    // agents per scene
static const int cL  = 640;   // cK*cNS attention length
static const int cHD = 32;    // head dim

#define CONV_TOTAL 977986

__constant__ int c_off[38] = {0,196608,212992,229376,229632,229888,557568,560128,562688,
  565248,630784,696320,696832,762368,827904,828416,844800,844928,861312,861440,877824,
  877952,910720,910976,943744,943872,960256,960384,960512,960640,960896,960960,977344,
  977472,977600,977728,977984,977986};
__constant__ int c_len[37] = {196608,16384,16384,256,256,327680,2560,2560,2560,
  65536,65536,512,65536,65536,512,16384,128,16384,128,16384,128,
  32768,256,32768,128,16384,128,128,128,256,2,16384,128,128,128,256,2};

struct Ptrs { const void* p[37]; };

__device__ __forceinline__ float sigm(float x){ return 1.f/(1.f+expf(-x)); }

// dtype sniffing + NaN canary
__global__ void k_detect(const unsigned short* ge_u16, int* flagp, unsigned int* outw){
  __shared__ int cnt;
  if (threadIdx.x == 0) cnt = 0;
  __syncthreads();
  int ok = 0;
  for (int i = threadIdx.x; i < 128; i += 64){
    unsigned short u = ge_u16[2*i];
    int ex = (u >> 7) & 0xFF;
    if (ex >= 100 && ex <= 140) ok++;
  }
  atomicAdd(&cnt, ok);
  __syncthreads();
  if (threadIdx.x == 0){
    *flagp = (cnt >= 96) ? 1 : 0;
    outw[0] = 0x7FC07FC0u;
  }
}

// convert all 37 inputs to fp32 into the conv region
__global__ void k_convert(Ptrs ptrs, const int* flagp, float* dst){
  int g = blockIdx.x*256 + threadIdx.x;
  if (g >= CONV_TOTAL) return;
  int flag = *flagp;
  int seg = 0;
  while (seg < 36 && g >= c_off[seg+1]) ++seg;
  int local = g - c_off[seg];
  if (local >= c_len[seg]) return;
  float v;
  if (flag) v = __bfloat162float(((const bf16_t*)ptrs.p[seg])[local]);
  else      v = ((const float*)ptrs.p[seg])[local];
  dst[g] = v;
}

// ge = relu(LN_2560(x @ mhp_W + b)), 2 rows per block, weight reuse across rows
__global__ void k_mhp(const float* x, const float* W, const float* b,
                      const float* g, const float* be, float* out){
  const int ROWS = 2;
  int r0 = blockIdx.x*ROWS;
  __shared__ float xs[ROWS][cH];
  __shared__ float red[256][3];
  int tid = threadIdx.x;
  if (tid < ROWS*32){
    int rr = tid>>5, u4 = tid&31;
    ((float4*)&xs[rr][0])[u4] = ((const float4*)x)[(r0+rr)*32 + u4];
  }
  __syncthreads();
  float y[ROWS][10];
  #pragma unroll
  for (int m = 0; m < 10; ++m){ float bb = b[tid + 256*m]; y[0][m] = bb; y[1][m] = bb; }
  for (int i = 0; i < cH; ++i){
    float x0 = xs[0][i], x1 = xs[1][i];
    const float* wr = W + i*2560 + tid;
    #pragma unroll
    for (int m = 0; m < 10; ++m){
      float w = wr[256*m];
      y[0][m] += x0*w; y[1][m] += x1*w;
    }
  }
  float ps0 = 0.f, ps1 = 0.f;
  #pragma unroll
  for (int m = 0; m < 10; ++m){ ps0 += y[0][m]; ps1 += y[1][m]; }
  red[tid][0] = ps0; red[tid][1] = ps1; __syncthreads();
  for (int s2 = 128; s2 > 0; s2 >>= 1){
    if (tid < s2){ red[tid][0] += red[tid+s2][0]; red[tid][1] += red[tid+s2][1]; }
    __syncthreads();
  }
  float mean0 = red[0][0]*(1.f/2560.f), mean1 = red[0][1]*(1.f/2560.f);
  __syncthreads();
  float pv0 = 0.f, pv1 = 0.f;
  #pragma unroll
  for (int m = 0; m < 10; ++m){
    float d0 = y[0][m]-mean0, d1 = y[1][m]-mean1;
    pv0 += d0*d0; pv1 += d1*d1;
  }
  red[tid][0] = pv0; red[tid][1] = pv1; __syncthreads();
  for (int s2 = 128; s2 > 0; s2 >>= 1){
    if (tid < s2){ red[tid][0] += red[tid+s2][0]; red[tid][1] += red[tid+s2][1]; }
    __syncthreads();
  }
  float inv0 = rsqrtf(red[0][0]*(1.f/2560.f) + 1e-5f);
  float inv1 = rsqrtf(red[0][1]*(1.f/2560.f) + 1e-5f);
  #pragma unroll
  for (int rr = 0; rr < ROWS; ++rr){
    int rg = r0 + rr;
    int t = rg >> 7, nn = rg & 127;
    float mean = rr ? mean1 : mean0;
    float inv  = rr ? inv1  : inv0;
    #pragma unroll
    for (int m = 0; m < 10; ++m){
      int col = tid + 256*m;
      float z = (y[rr][m]-mean)*inv*g[col] + be[col];
      z = fmaxf(z, 0.f);
      int k = col >> 7, hh2 = col & 127;
      out[((t*cKN) + k*cN + nn)*cH + hh2] = z;
    }
  }
}

// fused 12-step LSTM, 4 rows/block, h/c persistent in LDS; phase 2 adds soc/tanh.
__global__ void k_lstm_seq(const float* ge, float* outh,
    const float* hs0, const float* cn0, const float* soc,
    const float* Wih, const float* Whh, const float* bias, int phase){
  const int ROWS = 4;
  int r0 = blockIdx.x * ROWS;
  __shared__ float xs[ROWS][cH], hs[ROWS][cH], cs[ROWS][cH];
  int tid = threadIdx.x;
  if (tid < ROWS*32){
    int rr = tid>>5, u4 = tid&31;
    int nn = (r0+rr) & 127;
    ((float4*)&hs[rr][0])[u4] = ((const float4*)hs0)[nn*32 + u4];
    ((float4*)&cs[rr][0])[u4] = ((const float4*)cn0)[nn*32 + u4];
  }
  int u = tid & 127, half = tid >> 7;
  float b0 = bias[u], b1 = bias[128+u], b2 = bias[256+u], b3 = bias[384+u];
  for (int t = 0; t < cT; ++t){
    __syncthreads();   // orders previous step's hs/cs gate-writes vs this RMW
    if (tid < ROWS*32){
      int rr = tid>>5, u4 = tid&31;
      size_t gi4 = (size_t)t*cKN*32 + (size_t)(r0+rr)*32 + u4;
      ((float4*)&xs[rr][0])[u4] = ((const float4*)ge)[gi4];
      if (phase == 2){
        float4 sv = ((const float4*)soc)[gi4];
        float4 cv = ((float4*)&cs[rr][0])[u4];
        float4 hv = ((float4*)&hs[rr][0])[u4];
        cv.x += sv.x; cv.y += sv.y; cv.z += sv.z; cv.w += sv.w;
        hv.x += tanhf(cv.x); hv.y += tanhf(cv.y); hv.z += tanhf(cv.z); hv.w += tanhf(cv.w);
        ((float4*)&cs[rr][0])[u4] = cv;
        ((float4*)&hs[rr][0])[u4] = hv;
      }
    }
    __syncthreads();
    float a[2][4] = {{0.f,0.f,0.f,0.f},{0.f,0.f,0.f,0.f}};
    for (int i = 0; i < cH; ++i){
      const float* wr = Wih + i*512 + u;
      const float* vr = Whh + i*512 + u;
      float w0 = wr[0], w1 = wr[128], w2 = wr[256], w3 = wr[384];
      float v0 = vr[0], v1 = vr[128], v2 = vr[256], v3 = vr[384];
      #pragma unroll
      for (int q = 0; q < 2; ++q){
        int rr = half + 2*q;
        float xi = xs[rr][i], hi = hs[rr][i];
        a[q][0] += xi*w0 + hi*v0;
        a[q][1] += xi*w1 + hi*v1;
        a[q][2] += xi*w2 + hi*v2;
        a[q][3] += xi*w3 + hi*v3;
      }
    }
    __syncthreads();   // all dot reads of hs/cs done before overwrite
    #pragma unroll
    for (int q = 0; q < 2; ++q){
      int rr = half + 2*q;
      float ig = sigm(a[q][0]+b0), fg = sigm(a[q][1]+b1);
      float gg = tanhf(a[q][2]+b2), og = sigm(a[q][3]+b3);
      float c2 = fg*cs[rr][u] + ig*gg;
      float h2 = og*tanhf(c2);
      cs[rr][u] = c2; hs[rr][u] = h2;
      outh[(size_t)t*cKN*cH + (size_t)(r0+rr)*cH + u] = h2;
    }
  }
}

// loc & scale heads fused, 8 rows/block, weight reuse
__global__ void k_heads(const float* x,
  const float* lW1, const float* lb1, const float* lg, const float* lbe, const float* lW2, const float* lb2v,
  const float* sW1, const float* sb1, const float* sg, const float* sbe, const float* sW2, const float* sb2v,
  void* outv, int q0, float* locsc, const float* maxv, const float* svp, const int* flagp){
  const int ROWS = 8;
  int r0 = blockIdx.x*ROWS;
  __shared__ float xs[ROWS][cH];
  __shared__ float red[256][9];
  int tid = threadIdx.x;
  {
    int rr = tid>>5, u4 = tid&31;
    ((float4*)&xs[rr][0])[u4] = ((const float4*)x)[(size_t)(r0+rr)*32 + u4];
  }
  __syncthreads();
  int head = tid >> 7, j = tid & 127;
  const float* W1 = head ? sW1 : lW1;
  const float* b1 = head ? sb1 : lb1;
  const float* gv = head ? sg  : lg;
  const float* be = head ? sbe : lbe;
  const float* W2 = head ? sW2 : lW2;
  const float* b2 = head ? sb2v: lb2v;
  int base = head*128;
  float a[8];
  float bb = b1[j];
  #pragma unroll
  for (int r = 0; r < 8; ++r) a[r] = bb;
  for (int i = 0; i < cH; ++i){
    float w = W1[i*cH + j];
    #pragma unroll
    for (int r = 0; r < 8; ++r) a[r] += xs[r][i]*w;
  }
  #pragma unroll
  for (int r = 0; r < 8; ++r) red[tid][r] = a[r];
  __syncthreads();
  for (int s2 = 64; s2 > 0; s2 >>= 1){
    if ((tid&127) < s2){
      #pragma unroll
      for (int r = 0; r < 8; ++r) red[tid][r] += red[tid+s2][r];
    }
    __syncthreads();
  }
  float d[8];
  #pragma unroll
  for (int r = 0; r < 8; ++r) d[r] = a[r] - red[base][r]*(1.f/128.f);
  __syncthreads();
  #pragma unroll
  for (int r = 0; r < 8; ++r) red[tid][r] = d[r]*d[r];
  __syncthreads();
  for (int s2 = 64; s2 > 0; s2 >>= 1){
    if ((tid&127) < s2){
      #pragma unroll
      for (int r = 0; r < 8; ++r) red[tid][r] += red[tid+s2][r];
    }
    __syncthreads();
  }
  float z[8];
  float gj = gv[j], bej = be[j];
  #pragma unroll
  for (int r = 0; r < 8; ++r){
    float inv = rsqrtf(red[base][r]*(1.f/128.f) + 1e-5f);
    z[r] = fmaxf(d[r]*inv*gj + bej, 0.f);
  }
  __syncthreads();
  float w20 = W2[j*2+0], w21 = W2[j*2+1];
  #pragma unroll
  for (int r = 0; r < 8; ++r) red[tid][r] = z[r]*w20;
  __syncthreads();
  for (int s2 = 64; s2 > 0; s2 >>= 1){
    if ((tid&127) < s2){
      #pragma unroll
      for (int r = 0; r < 8; ++r) red[tid][r] += red[tid+s2][r];
    }
    __syncthreads();
  }
  float o0[8];
  #pragma unroll
  for (int r = 0; r < 8; ++r) o0[r] = red[base][r] + b2[0];
  __syncthreads();
  #pragma unroll
  for (int r = 0; r < 8; ++r) red[tid][r] = z[r]*w21;
  __syncthreads();
  for (int s2 = 64; s2 > 0; s2 >>= 1){
    if ((tid&127) < s2){
      #pragma unroll
      for (int r = 0; r < 8; ++r) red[tid][r] += red[tid+s2][r];
    }
    __syncthreads();
  }
  if (j == 0){
    int flag = *flagp;
    for (int r = 0; r < 8; ++r){
      float v0 = o0[r];
      float v1 = red[base][r] + b2[1];
      int rg = r0 + r;
      int t = rg / cKN, rem = rg - t*cKN;
      int k = rem >> 7, nn = rem & 127;
      if (head == 0){
        size_t oi = (((size_t)q0*cK + k)*cN + nn)*(cT*2) + t*2;
        if (flag){ ((bf16_t*)outv)[oi] = __float2bfloat16(v0); ((bf16_t*)outv)[oi+1] = __float2bfloat16(v1); }
        else     { ((float*)outv)[oi] = v0; ((float*)outv)[oi+1] = v1; }
        if (locsc){
          locsc[((size_t)t*cKN + rem)*2 + 0] = v0*maxv[nn*2+0] + svp[nn*2+0];
          locsc[((size_t)t*cKN + rem)*2 + 1] = v1*maxv[nn*2+1] + svp[nn*2+1];
        }
      } else {
        float e0 = (v0 > 0.f ? v0 : expm1f(v0)) + 1.001f;
        float e1 = (v1 > 0.f ? v1 : expm1f(v1)) + 1.001f;
        size_t oi = (((size_t)(q0+1)*cK + k)*cN + nn)*(cT*2) + t*2;
        if (flag){ ((bf16_t*)outv)[oi] = __float2bfloat16(e0); ((bf16_t*)outv)[oi+1] = __float2bfloat16(e1); }
        else     { ((float*)outv)[oi] = e0; ((float*)outv)[oi+1] = e1; }
      }
    }
  }
}

__global__ void k_mask(const float* locsc, unsigned char* m){
  int st = blockIdx.x;
  int s = st / cT, t = st - s*cT;
  __shared__ float lx[cK][cNS], ly[cK][cNS];
  int tid = threadIdx.x;
  for (int p = tid; p < cK*cNS; p += 256){
    int k = p >> 5, i = p & 31;
    int row = t*cKN + k*cN + s*cNS + i;
    lx[k][i] = locsc[row*2+0];
    ly[k][i] = locsc[row*2+1];
  }
  __syncthreads();
  for (int p = tid; p < 1024; p += 256){
    int i = p >> 5, j = p & 31;
    bool any = false;
    for (int k = 0; k < cK; ++k){
      float dx = fabsf(lx[k][i]-lx[k][j]);
      float dy = fabsf(ly[k][i]-ly[k][j]);
      any = any || ((dx < 10.f) && (dy < 10.f));
    }
    m[st*1024 + p] = any ? 1 : 0;
  }
}

// QKV projection, 16 rows/block, weight reuse for 8 rows/thread
__global__ void k_qkv(const float* x,
  const float* Wq, const float* bq, const float* Wk, const float* bk,
  const float* Wv, const float* bv,
  float* Q, float* K2, float* V){
  const int ROWS = 16;
  int r0 = blockIdx.x*ROWS;
  __shared__ float xs[ROWS][cH];
  int tid = threadIdx.x;
  for (int p = tid; p < ROWS*32; p += 256){
    int rr = p>>5, u4 = p&31;
    ((float4*)&xs[rr][0])[u4] = ((const float4*)x)[(size_t)(r0+rr)*32 + u4];
  }
  __syncthreads();
  int cl = tid & 127, half = tid >> 7;
  float aq[8], ak[8], av[8];
  float bq0 = bq[cl], bk0 = bk[cl], bv0 = bv[cl];
  #pragma unroll
  for (int r = 0; r < 8; ++r){ aq[r] = bq0; ak[r] = bk0; av[r] = bv0; }
  for (int i = 0; i < cH; ++i){
    float wq = Wq[i*cH+cl], wk = Wk[i*cH+cl], wv = Wv[i*cH+cl];
    #pragma unroll
    for (int q2 = 0; q2 < 8; ++q2){
      float xi = xs[half + 2*q2][i];
      aq[q2] += xi*wq; ak[q2] += xi*wk; av[q2] += xi*wv;
    }
  }
  #pragma unroll
  for (int q2 = 0; q2 < 8; ++q2){
    size_t gi = (size_t)(r0 + half + 2*q2)*cH + cl;
    Q[gi] = aq[q2]; K2[gi] = ak[q2]; V[gi] = av[q2];
  }
}

// flash-style masked MHSA v3: 64 q-rows/block, 4x4 register tiling (QK) and
// 4x2 (PV), Q staged once in LDS, bitmask masks in registers, online softmax,
// double-buffered K/V staging, 2 barriers per 64-key tile.
// __launch_bounds__(256) is REQUIRED: without it hipcc caps VGPRs at the
// 1024-thread default and spills ~2KB/thread/tile to scratch (15 GB of HBM
// traffic, 8x slowdown -- measured round 7).
__global__ __launch_bounds__(256) void k_attn(const float* Q, const float* Kx, const float* V,
                       const unsigned char* msk, float* ctx){
  int tile = blockIdx.x;        // 0..9 (64 q-rows each)
  int head = blockIdx.y;        // 0..3
  int st   = blockIdx.z;        // s*cT + t
  int s = st / cT, t = st - s*cT;
  __shared__ float Qs[64][36];           // 9216 B
  __shared__ float Kb[2][64][36];        // 18432 B
  __shared__ float Vt[2][32][68];        // 17408 B (V transposed per tile)
  __shared__ float Pb[64][68];           // 17408 B
  __shared__ unsigned int ml32[32];      // 128 B   (total 62592 B)
  int tid = threadIdx.x;
  int i = tid >> 4, j = tid & 15;
  int l0 = tile*64;
  // build per-agent mask bitmasks
  if (tid < 32){
    unsigned int m = 0;
    const unsigned char* mr = msk + st*1024 + tid*32;
    #pragma unroll
    for (int jj = 0; jj < 32; ++jj) m |= (mr[jj] ? 1u : 0u) << jj;
    ml32[tid] = m;
  }
  int kk_a = tid >> 3, f4_a = tid & 7;   // staging slots: rows kk_a, kk_a+32
  // stage Q (64 rows x 32 dims)
  {
    int l = l0 + kk_a;
    int grow = t*cKN + (l>>5)*cN + s*cNS + (l&31);
    ((float4*)&Qs[kk_a][0])[f4_a] = ((const float4*)Q)[(size_t)grow*32 + head*8 + f4_a];
    l = l0 + kk_a + 32;
    grow = t*cKN + (l>>5)*cN + s*cNS + (l&31);
    ((float4*)&Qs[kk_a+32][0])[f4_a] = ((const float4*)Q)[(size_t)grow*32 + head*8 + f4_a];
  }
  const float scl = 0.17677669529663687f;   // 1/sqrt(32)

  #define KADDR(c0,kk,f4) ((const float4*)Kx + (size_t)(t*cKN + (((c0)+(kk))>>5)*cN + s*cNS + (((c0)+(kk))&31))*32 + head*8 + (f4))
  #define VADDR(c0,kk,f4) ((const float4*)V  + (size_t)(t*cKN + (((c0)+(kk))>>5)*cN + s*cNS + (((c0)+(kk))&31))*32 + head*8 + (f4))

  float4 kpre0 = *KADDR(0, kk_a, f4_a);
  float4 kpre1 = *KADDR(0, kk_a+32, f4_a);
  float4 vpre0 = *VADDR(0, kk_a, f4_a);
  float4 vpre1 = *VADDR(0, kk_a+32, f4_a);
  {
    ((float4*)&Kb[0][kk_a][0])[f4_a] = kpre0;
    ((float4*)&Kb[0][kk_a+32][0])[f4_a] = kpre1;
    int d0 = f4_a*4;
    Vt[0][d0+0][kk_a] = vpre0.x; Vt[0][d0+1][kk_a] = vpre0.y;
    Vt[0][d0+2][kk_a] = vpre0.z; Vt[0][d0+3][kk_a] = vpre0.w;
    Vt[0][d0+0][kk_a+32] = vpre1.x; Vt[0][d0+1][kk_a+32] = vpre1.y;
    Vt[0][d0+2][kk_a+32] = vpre1.z; Vt[0][d0+3][kk_a+32] = vpre1.w;
  }
  __syncthreads();

  // per-thread row masks: rows 4i..4i+3, key-agent nibble (4j..4j+3)
  unsigned int nib[4];
  #pragma unroll
  for (int r = 0; r < 4; ++r){
    unsigned int mrow = ml32[(4*i + r) & 31];
    nib[r] = (mrow >> ((4*j) & 31)) & 0xFu;
  }
  float m_run[4] = {-3.4e38f,-3.4e38f,-3.4e38f,-3.4e38f};
  float l_run[4] = {0.f,0.f,0.f,0.f};
  float O[4][2] = {{0.f,0.f},{0.f,0.f},{0.f,0.f},{0.f,0.f}};

  for (int c = 0; c < 10; ++c){
    int par = c & 1;
    if (c < 9){
      int c1 = (c+1)*64;
      kpre0 = *KADDR(c1, kk_a, f4_a);
      kpre1 = *KADDR(c1, kk_a+32, f4_a);
      vpre0 = *VADDR(c1, kk_a, f4_a);
      vpre1 = *VADDR(c1, kk_a+32, f4_a);
    }
    // QK: 4 rows x 4 keys per thread
    float sc[4][4] = {{0,0,0,0},{0,0,0,0},{0,0,0,0},{0,0,0,0}};
    #pragma unroll
    for (int ch = 0; ch < 8; ++ch){
      float4 q0 = ((const float4*)&Qs[4*i+0][0])[ch];
      float4 q1 = ((const float4*)&Qs[4*i+1][0])[ch];
      float4 q2 = ((const float4*)&Qs[4*i+2][0])[ch];
      float4 q3 = ((const float4*)&Qs[4*i+3][0])[ch];
      #pragma unroll
      for (int kk = 0; kk < 4; ++kk){
        float4 kv = ((const float4*)&Kb[par][4*j+kk][0])[ch];
        sc[0][kk] += q0.x*kv.x + q0.y*kv.y + q0.z*kv.z + q0.w*kv.w;
        sc[1][kk] += q1.x*kv.x + q1.y*kv.y + q1.z*kv.z + q1.w*kv.w;
        sc[2][kk] += q2.x*kv.x + q2.y*kv.y + q2.z*kv.z + q2.w*kv.w;
        sc[3][kk] += q3.x*kv.x + q3.y*kv.y + q3.z*kv.z + q3.w*kv.w;
      }
    }
    // online softmax per row
    #pragma unroll
    for (int r = 0; r < 4; ++r){
      float sv[4];
      #pragma unroll
      for (int kk = 0; kk < 4; ++kk)
        sv[kk] = ((nib[r] >> kk) & 1u) ? sc[r][kk]*scl : -3.4e38f;
      float tmax = fmaxf(fmaxf(sv[0],sv[1]), fmaxf(sv[2],sv[3]));
      #pragma unroll
      for (int off = 1; off < 16; off <<= 1)
        tmax = fmaxf(tmax, __shfl_xor(tmax, off, 16));
      float m_new = fmaxf(m_run[r], tmax);
      float alpha = expf(m_run[r] - m_new);
      float p[4], psum = 0.f;
      #pragma unroll
      for (int kk = 0; kk < 4; ++kk){
        p[kk] = ((nib[r] >> kk) & 1u) ? expf(sv[kk] - m_new) : 0.f;
        psum += p[kk];
      }
      #pragma unroll
      for (int off = 1; off < 16; off <<= 1)
        psum += __shfl_xor(psum, off, 16);
      l_run[r] = l_run[r]*alpha + psum;
      m_run[r] = m_new;
      O[r][0] *= alpha; O[r][1] *= alpha;
      float4 p4; p4.x = p[0]; p4.y = p[1]; p4.z = p[2]; p4.w = p[3];
      ((float4*)&Pb[4*i+r][0])[j] = p4;
    }
    __syncthreads();   // Pb visible; Kb[par] reads done
    // PV: rows 4i..4i+3 x dims 2j, 2j+1
    #pragma unroll
    for (int m = 0; m < 16; ++m){
      float4 v0 = ((const float4*)&Vt[par][2*j+0][0])[m];
      float4 v1 = ((const float4*)&Vt[par][2*j+1][0])[m];
      #pragma unroll
      for (int r = 0; r < 4; ++r){
        float4 pv = ((const float4*)&Pb[4*i+r][0])[m];
        O[r][0] += pv.x*v0.x + pv.y*v0.y + pv.z*v0.z + pv.w*v0.w;
        O[r][1] += pv.x*v1.x + pv.y*v1.y + pv.z*v1.z + pv.w*v1.w;
      }
    }
    if (c < 9){
      int nb = 1 - par;
      ((float4*)&Kb[nb][kk_a][0])[f4_a] = kpre0;
      ((float4*)&Kb[nb][kk_a+32][0])[f4_a] = kpre1;
      int d0 = f4_a*4;
      Vt[nb][d0+0][kk_a] = vpre0.x; Vt[nb][d0+1][kk_a] = vpre0.y;
      Vt[nb][d0+2][kk_a] = vpre0.z; Vt[nb][d0+3][kk_a] = vpre0.w;
      Vt[nb][d0+0][kk_a+32] = vpre1.x; Vt[nb][d0+1][kk_a+32] = vpre1.y;
      Vt[nb][d0+2][kk_a+32] = vpre1.z; Vt[nb][d0+3][kk_a+32] = vpre1.w;
    }
    __syncthreads();   // PV reads of Pb/Vt done; staging writes done
  }
  #undef KADDR
  #undef VADDR
  #pragma unroll
  for (int r = 0; r < 4; ++r){
    float rinv = 1.f / l_run[r];
    int l = l0 + 4*i + r;
    int grow = t*cKN + (l>>5)*cN + s*cNS + (l&31);
    float2 o2; o2.x = O[r][0]*rinv; o2.y = O[r][1]*rinv;
    ((float2*)(ctx + (size_t)grow*cH + head*cHD))[j] = o2;
  }
}

// Wo1 + relu, 8 rows/block, weight reuse
__global__ void k_wo1(const float* x, const float* W, const float* b, float* o){
  const int ROWS = 8;
  int r0 = blockIdx.x*ROWS;
  __shared__ float xs[ROWS][cH];
  int tid = threadIdx.x;
  {
    int rr = tid>>5, u4 = tid&31;
    ((float4*)&xs[rr][0])[u4] = ((const float4*)x)[(size_t)(r0+rr)*32 + u4];
  }
  __syncthreads();
  float a[8];
  float bb = b[tid];
  #pragma unroll
  for (int r = 0; r < 8; ++r) a[r] = bb;
  for (int i = 0; i < cH; ++i){
    float w = W[i*256 + tid];
    #pragma unroll
    for (int r = 0; r < 8; ++r) a[r] += xs[r][i]*w;
  }
  #pragma unroll
  for (int r = 0; r < 8; ++r) o[(size_t)(r0+r)*256 + tid] = fmaxf(a[r], 0.f);
}

// Wo2, 16 rows/block, weight reuse
__global__ void k_wo2(const float* x, const float* W, const float* b, float* o){
  const int ROWS = 16;
  int r0 = blockIdx.x*ROWS;
  __shared__ float xs[ROWS][256];
  int tid = threadIdx.x;
  for (int p = tid; p < ROWS*64; p += 256){
    int rr = p>>6, u4 = p&63;
    ((float4*)&xs[rr][0])[u4] = ((const float4*)x)[(size_t)(r0+rr)*64 + u4];
  }
  __syncthreads();
  int cl = tid & 127, half = tid >> 7;
  float a[8];
  float bb = b[cl];
  #pragma unroll
  for (int r = 0; r < 8; ++r) a[r] = bb;
  for (int i = 0; i < 256; ++i){
    float w = W[i*cH + cl];
    #pragma unroll
    for (int q2 = 0; q2 < 8; ++q2) a[q2] += xs[half + 2*q2][i]*w;
  }
  #pragma unroll
  for (int q2 = 0; q2 < 8; ++q2) o[(size_t)(r0 + half + 2*q2)*cH + cl] = a[q2];
}

extern "C" void kernel_launch(void* const* d_in, const int* in_sizes, int n_in,
                              void* d_out, int out_size, void* d_ws, size_t ws_size,
                              hipStream_t stream){
  (void)in_sizes; (void)n_in; (void)out_size; (void)ws_size;

  int*   flagp = (int*)d_ws;
  float* conv  = (float*)d_ws + 64;
  float* big   = (float*)d_ws + 978112;

  const float* ge_f   = conv + 0;
  const float* hs_f   = conv + 196608;
  const float* cn_f   = conv + 212992;
  const float* sv_f   = conv + 229376;
  const float* mx_f   = conv + 229632;
  const float* mhpW_f = conv + 229888;
  const float* mhpb_f = conv + 557568;
  const float* mhpg_f = conv + 560128;
  const float* mhpbe_f= conv + 562688;
  const float* l1Wih_f= conv + 565248;
  const float* l1Whh_f= conv + 630784;
  const float* l1b_f  = conv + 696320;
  const float* l2Wih_f= conv + 696832;
  const float* l2Whh_f= conv + 762368;
  const float* l2b_f  = conv + 827904;
  const float* Wq_f   = conv + 828416;
  const float* bq_f   = conv + 844800;
  const float* Wk_f   = conv + 844928;
  const float* bk_f   = conv + 861312;
  const float* Wv_f   = conv + 861440;
  const float* bv_f   = conv + 877824;
  const float* Wo1_f  = conv + 877952;
  const float* bo1_f  = conv + 910720;
  const float* Wo2_f  = conv + 910976;
  const float* bo2_f  = conv + 943744;
  const float* locW1_f= conv + 943872;
  const float* locb1_f= conv + 960256;
  const float* locg_f = conv + 960384;
  const float* locbe_f= conv + 960512;
  const float* locW2_f= conv + 960640;
  const float* locb2_f= conv + 960896;
  const float* sclW1_f= conv + 960960;
  const float* sclb1_f= conv + 977344;
  const float* sclg_f = conv + 977472;
  const float* sclbe_f= conv + 977600;
  const float* sclW2_f= conv + 977728;
  const float* sclb2_f= conv + 977984;

  const size_t SLOT = (size_t)cT*cKN*cH;
  float* geb = big;
  float* o1b = big + SLOT;
  float* Qb  = big + 2*SLOT;
  float* Kb  = big + 3*SLOT;
  float* Vb  = big + 4*SLOT;
  float* locsc = big + 5*SLOT;
  unsigned char* maskb = (unsigned char*)(locsc + (size_t)cT*cKN*2);
  float* t1 = Qb;        // spans slots 2-3 (Q/K dead after attn)
  float* social = Vb;    // overlays V after attention

  Ptrs ptrs;
  for (int i = 0; i < 37; ++i) ptrs.p[i] = d_in[i];

  k_detect<<<1, 64, 0, stream>>>((const unsigned short*)d_in[0], flagp, (unsigned int*)d_out);
  k_convert<<<(CONV_TOTAL+255)/256, 256, 0, stream>>>(ptrs, flagp, conv);
  k_mhp<<<cT*cN/2, 256, 0, stream>>>(ge_f, mhpW_f, mhpb_f, mhpg_f, mhpbe_f, geb);
  k_lstm_seq<<<cKN/4, 256, 0, stream>>>(geb, o1b, hs_f, cn_f, (const float*)0,
                                        l1Wih_f, l1Whh_f, l1b_f, 1);
  k_heads<<<cT*cKN/8, 256, 0, stream>>>(o1b, locW1_f,locb1_f,locg_f,locbe_f,locW2_f,locb2_f,
                                        sclW1_f,sclb1_f,sclg_f,sclbe_f,sclW2_f,sclb2_f,
                                        d_out, 0, locsc, mx_f, sv_f, flagp);
  k_mask<<<cS*cT, 256, 0, stream>>>(locsc, maskb);
  k_qkv<<<cT*cKN/16, 256, 0, stream>>>(o1b, Wq_f,bq_f, Wk_f,bk_f, Wv_f,bv_f, Qb, Kb, Vb);
  {
    dim3 ag(cL/64, 4, cS*cT);
    k_attn<<<ag, 256, 0, stream>>>(Qb, Kb, Vb, maskb, o1b);   // ctx overlays out1
  }
  k_wo1<<<cT*cKN/8, 256, 0, stream>>>(o1b, Wo1_f, bo1_f, t1);
  k_wo2<<<cT*cKN/16, 256, 0, stream>>>(t1, Wo2_f, bo2_f, social);
  k_lstm_seq<<<cKN/4, 256, 0, stream>>>(geb, o1b, hs_f, cn_f, social,
                                        l2Wih_f, l2Whh_f, l2b_f, 2);
  k_heads<<<cT*cKN/8, 256, 0, stream>>>(o1b, locW1_f,locb1_f,locg_f,locbe_f,locW2_f,locb2_f,
                                        sclW1_f,sclb1_f,sclg_f,sclbe_f,sclW2_f,sclb2_f,
                                        d_out, 2, (float*)0, mx_f, sv_f, flagp);
}

// Round 9
// 1463.457 us; speedup vs baseline: 3.1052x; 1.1620x over previous
//
#include <hip/hip_runtime.h>
#include <hip/hip_bf16.h>

typedef __hip_bfloat16 bf16_t;

static const int cT  = 12;    // future steps
static const int cN  = 128;   // agents
static const int cH  = 128;   // hidden
static const int cK  = 20;    // modes
static const int cKN = 2560;  // cK*cN
static const int cS  = 4;     // batch split
static const int cNS = 32;    // agents per scene
static const int cL  = 640;   // cK*cNS attention length
static const int cHD = 32;    // head dim

#define CONV_TOTAL 977986

__constant__ int c_off[38] = {0,196608,212992,229376,229632,229888,557568,560128,562688,
  565248,630784,696320,696832,762368,827904,828416,844800,844928,861312,861440,877824,
  877952,910720,910976,943744,943872,960256,960384,960512,960640,960896,960960,977344,
  977472,977600,977728,977984,977986};
__constant__ int c_len[37] = {196608,16384,16384,256,256,327680,2560,2560,2560,
  65536,65536,512,65536,65536,512,16384,128,16384,128,16384,128,
  32768,256,32768,128,16384,128,128,128,256,2,16384,128,128,128,256,2};

struct Ptrs { const void* p[37]; };

__device__ __forceinline__ float sigm(float x){ return 1.f/(1.f+expf(-x)); }

// dtype sniffing + NaN canary
__global__ __launch_bounds__(256) void k_detect(const unsigned short* ge_u16, int* flagp, unsigned int* outw){
  __shared__ int cnt;
  if (threadIdx.x == 0) cnt = 0;
  __syncthreads();
  int ok = 0;
  for (int i = threadIdx.x; i < 128; i += 64){
    unsigned short u = ge_u16[2*i];
    int ex = (u >> 7) & 0xFF;
    if (ex >= 100 && ex <= 140) ok++;
  }
  atomicAdd(&cnt, ok);
  __syncthreads();
  if (threadIdx.x == 0){
    *flagp = (cnt >= 96) ? 1 : 0;
    outw[0] = 0x7FC07FC0u;
  }
}

// convert all 37 inputs to fp32 into the conv region
__global__ __launch_bounds__(256) void k_convert(Ptrs ptrs, const int* flagp, float* dst){
  int g = blockIdx.x*256 + threadIdx.x;
  if (g >= CONV_TOTAL) return;
  int flag = *flagp;
  int seg = 0;
  while (seg < 36 && g >= c_off[seg+1]) ++seg;
  int local = g - c_off[seg];
  if (local >= c_len[seg]) return;
  float v;
  if (flag) v = __bfloat162float(((const bf16_t*)ptrs.p[seg])[local]);
  else      v = ((const float*)ptrs.p[seg])[local];
  dst[g] = v;
}

// ge = relu(LN_2560(x @ mhp_W + b)), 2 rows per block, weight reuse across rows
__global__ __launch_bounds__(256) void k_mhp(const float* x, const float* W, const float* b,
                      const float* g, const float* be, float* out){
  const int ROWS = 2;
  int r0 = blockIdx.x*ROWS;
  __shared__ float xs[ROWS][cH];
  __shared__ float red[256][3];
  int tid = threadIdx.x;
  if (tid < ROWS*32){
    int rr = tid>>5, u4 = tid&31;
    ((float4*)&xs[rr][0])[u4] = ((const float4*)x)[(r0+rr)*32 + u4];
  }
  __syncthreads();
  float y[ROWS][10];
  #pragma unroll
  for (int m = 0; m < 10; ++m){ float bb = b[tid + 256*m]; y[0][m] = bb; y[1][m] = bb; }
  for (int i = 0; i < cH; ++i){
    float x0 = xs[0][i], x1 = xs[1][i];
    const float* wr = W + i*2560 + tid;
    #pragma unroll
    for (int m = 0; m < 10; ++m){
      float w = wr[256*m];
      y[0][m] += x0*w; y[1][m] += x1*w;
    }
  }
  float ps0 = 0.f, ps1 = 0.f;
  #pragma unroll
  for (int m = 0; m < 10; ++m){ ps0 += y[0][m]; ps1 += y[1][m]; }
  red[tid][0] = ps0; red[tid][1] = ps1; __syncthreads();
  for (int s2 = 128; s2 > 0; s2 >>= 1){
    if (tid < s2){ red[tid][0] += red[tid+s2][0]; red[tid][1] += red[tid+s2][1]; }
    __syncthreads();
  }
  float mean0 = red[0][0]*(1.f/2560.f), mean1 = red[0][1]*(1.f/2560.f);
  __syncthreads();
  float pv0 = 0.f, pv1 = 0.f;
  #pragma unroll
  for (int m = 0; m < 10; ++m){
    float d0 = y[0][m]-mean0, d1 = y[1][m]-mean1;
    pv0 += d0*d0; pv1 += d1*d1;
  }
  red[tid][0] = pv0; red[tid][1] = pv1; __syncthreads();
  for (int s2 = 128; s2 > 0; s2 >>= 1){
    if (tid < s2){ red[tid][0] += red[tid+s2][0]; red[tid][1] += red[tid+s2][1]; }
    __syncthreads();
  }
  float inv0 = rsqrtf(red[0][0]*(1.f/2560.f) + 1e-5f);
  float inv1 = rsqrtf(red[0][1]*(1.f/2560.f) + 1e-5f);
  #pragma unroll
  for (int rr = 0; rr < ROWS; ++rr){
    int rg = r0 + rr;
    int t = rg >> 7, nn = rg & 127;
    float mean = rr ? mean1 : mean0;
    float inv  = rr ? inv1  : inv0;
    #pragma unroll
    for (int m = 0; m < 10; ++m){
      int col = tid + 256*m;
      float z = (y[rr][m]-mean)*inv*g[col] + be[col];
      z = fmaxf(z, 0.f);
      int k = col >> 7, hh2 = col & 127;
      out[((t*cKN) + k*cN + nn)*cH + hh2] = z;
    }
  }
}

// fused 12-step LSTM, 8 rows/block (halves L2 weight traffic vs 4), h/c in LDS.
__global__ __launch_bounds__(256) void k_lstm_seq(const float* ge, float* outh,
    const float* hs0, const float* cn0, const float* soc,
    const float* Wih, const float* Whh, const float* bias, int phase){
  const int ROWS = 8;
  int r0 = blockIdx.x * ROWS;
  __shared__ float xs[ROWS][cH], hs[ROWS][cH], cs[ROWS][cH];
  int tid = threadIdx.x;
  {
    int rr = tid>>5, u4 = tid&31;
    int nn = (r0+rr) & 127;
    ((float4*)&hs[rr][0])[u4] = ((const float4*)hs0)[nn*32 + u4];
    ((float4*)&cs[rr][0])[u4] = ((const float4*)cn0)[nn*32 + u4];
  }
  int u = tid & 127, half = tid >> 7;
  float b0 = bias[u], b1 = bias[128+u], b2 = bias[256+u], b3 = bias[384+u];
  for (int t = 0; t < cT; ++t){
    __syncthreads();   // orders previous step's hs/cs gate-writes vs this RMW
    {
      int rr = tid>>5, u4 = tid&31;
      size_t gi4 = (size_t)t*cKN*32 + (size_t)(r0+rr)*32 + u4;
      ((float4*)&xs[rr][0])[u4] = ((const float4*)ge)[gi4];
      if (phase == 2){
        float4 sv = ((const float4*)soc)[gi4];
        float4 cv = ((float4*)&cs[rr][0])[u4];
        float4 hv = ((float4*)&hs[rr][0])[u4];
        cv.x += sv.x; cv.y += sv.y; cv.z += sv.z; cv.w += sv.w;
        hv.x += tanhf(cv.x); hv.y += tanhf(cv.y); hv.z += tanhf(cv.z); hv.w += tanhf(cv.w);
        ((float4*)&cs[rr][0])[u4] = cv;
        ((float4*)&hs[rr][0])[u4] = hv;
      }
    }
    __syncthreads();
    float a[4][4] = {{0,0,0,0},{0,0,0,0},{0,0,0,0},{0,0,0,0}};
    for (int i = 0; i < cH; ++i){
      const float* wr = Wih + i*512 + u;
      const float* vr = Whh + i*512 + u;
      float w0 = wr[0], w1 = wr[128], w2 = wr[256], w3 = wr[384];
      float v0 = vr[0], v1 = vr[128], v2 = vr[256], v3 = vr[384];
      #pragma unroll
      for (int q = 0; q < 4; ++q){
        int rr = half + 2*q;
        float xi = xs[rr][i], hi = hs[rr][i];
        a[q][0] += xi*w0 + hi*v0;
        a[q][1] += xi*w1 + hi*v1;
        a[q][2] += xi*w2 + hi*v2;
        a[q][3] += xi*w3 + hi*v3;
      }
    }
    __syncthreads();   // all dot reads of hs/cs done before overwrite
    #pragma unroll
    for (int q = 0; q < 4; ++q){
      int rr = half + 2*q;
      float ig = sigm(a[q][0]+b0), fg = sigm(a[q][1]+b1);
      float gg = tanhf(a[q][2]+b2), og = sigm(a[q][3]+b3);
      float c2 = fg*cs[rr][u] + ig*gg;
      float h2 = og*tanhf(c2);
      cs[rr][u] = c2; hs[rr][u] = h2;
      outh[(size_t)t*cKN*cH + (size_t)(r0+rr)*cH + u] = h2;
    }
  }
}

// loc & scale heads, wave-local: wave = (head, row-pair), shfl reductions, no trees.
__global__ __launch_bounds__(256) void k_heads(const float* x,
  const float* lW1, const float* lb1, const float* lg, const float* lbe, const float* lW2, const float* lb2v,
  const float* sW1, const float* sb1, const float* sg, const float* sbe, const float* sW2, const float* sb2v,
  void* outv, int q0, float* locsc, const float* maxv, const float* svp, const int* flagp){
  const int ROWS = 4;
  int r0 = blockIdx.x*ROWS;
  __shared__ float xs[ROWS][cH];
  int tid = threadIdx.x;
  if (tid < ROWS*32){
    int rr = tid>>5, u4 = tid&31;
    ((float4*)&xs[rr][0])[u4] = ((const float4*)x)[(size_t)(r0+rr)*32 + u4];
  }
  __syncthreads();
  int wv = tid >> 6, lane = tid & 63;
  int head = wv & 1;
  int ra = (wv >> 1)*2, rb = ra + 1;     // local rows
  const float* W1 = head ? sW1 : lW1;
  const float* b1 = head ? sb1 : lb1;
  const float* gv = head ? sg  : lg;
  const float* be = head ? sbe : lbe;
  const float* W2 = head ? sW2 : lW2;
  const float* b2 = head ? sb2v: lb2v;
  int j0 = lane, j1 = lane + 64;
  float a00 = b1[j0], a01 = b1[j1];
  float a10 = a00, a11 = a01;
  for (int i = 0; i < cH; ++i){
    float w0 = W1[i*cH + j0], w1 = W1[i*cH + j1];
    float xa = xs[ra][i], xb = xs[rb][i];
    a00 += xa*w0; a01 += xa*w1;
    a10 += xb*w0; a11 += xb*w1;
  }
  float s0 = a00 + a01, s1 = a10 + a11;
  #pragma unroll
  for (int off = 1; off < 64; off <<= 1){
    s0 += __shfl_xor(s0, off);
    s1 += __shfl_xor(s1, off);
  }
  float mean0 = s0*(1.f/128.f), mean1 = s1*(1.f/128.f);
  float d00 = a00-mean0, d01 = a01-mean0, d10 = a10-mean1, d11 = a11-mean1;
  float v0 = d00*d00 + d01*d01, v1 = d10*d10 + d11*d11;
  #pragma unroll
  for (int off = 1; off < 64; off <<= 1){
    v0 += __shfl_xor(v0, off);
    v1 += __shfl_xor(v1, off);
  }
  float inv0 = rsqrtf(v0*(1.f/128.f) + 1e-5f);
  float inv1 = rsqrtf(v1*(1.f/128.f) + 1e-5f);
  float g0 = gv[j0], g1 = gv[j1], be0 = be[j0], be1 = be[j1];
  float z00 = fmaxf(d00*inv0*g0 + be0, 0.f);
  float z01 = fmaxf(d01*inv0*g1 + be1, 0.f);
  float z10 = fmaxf(d10*inv1*g0 + be0, 0.f);
  float z11 = fmaxf(d11*inv1*g1 + be1, 0.f);
  float w2a0 = W2[j0*2+0], w2a1 = W2[j0*2+1];
  float w2b0 = W2[j1*2+0], w2b1 = W2[j1*2+1];
  float oa0 = z00*w2a0 + z01*w2b0;   // row ra, out 0
  float oa1 = z00*w2a1 + z01*w2b1;   // row ra, out 1
  float ob0 = z10*w2a0 + z11*w2b0;
  float ob1 = z10*w2a1 + z11*w2b1;
  #pragma unroll
  for (int off = 1; off < 64; off <<= 1){
    oa0 += __shfl_xor(oa0, off);
    oa1 += __shfl_xor(oa1, off);
    ob0 += __shfl_xor(ob0, off);
    ob1 += __shfl_xor(ob1, off);
  }
  if (lane == 0){
    int flag = *flagp;
    float bias0 = b2[0], bias1 = b2[1];
    float ro[2][2] = {{oa0 + bias0, oa1 + bias1},{ob0 + bias0, ob1 + bias1}};
    int lr[2] = {ra, rb};
    for (int e = 0; e < 2; ++e){
      int rg = r0 + lr[e];
      int t = rg / cKN, rem = rg - t*cKN;
      int k = rem >> 7, nn = rem & 127;
      float u0 = ro[e][0], u1 = ro[e][1];
      if (head == 0){
        size_t oi = (((size_t)q0*cK + k)*cN + nn)*(cT*2) + t*2;
        if (flag){ ((bf16_t*)outv)[oi] = __float2bfloat16(u0); ((bf16_t*)outv)[oi+1] = __float2bfloat16(u1); }
        else     { ((float*)outv)[oi] = u0; ((float*)outv)[oi+1] = u1; }
        if (locsc){
          locsc[((size_t)t*cKN + rem)*2 + 0] = u0*maxv[nn*2+0] + svp[nn*2+0];
          locsc[((size_t)t*cKN + rem)*2 + 1] = u1*maxv[nn*2+1] + svp[nn*2+1];
        }
      } else {
        float e0 = (u0 > 0.f ? u0 : expm1f(u0)) + 1.001f;
        float e1 = (u1 > 0.f ? u1 : expm1f(u1)) + 1.001f;
        size_t oi = (((size_t)(q0+1)*cK + k)*cN + nn)*(cT*2) + t*2;
        if (flag){ ((bf16_t*)outv)[oi] = __float2bfloat16(e0); ((bf16_t*)outv)[oi+1] = __float2bfloat16(e1); }
        else     { ((float*)outv)[oi] = e0; ((float*)outv)[oi+1] = e1; }
      }
    }
  }
}

__global__ __launch_bounds__(256) void k_mask(const float* locsc, unsigned char* m){
  int st = blockIdx.x;
  int s = st / cT, t = st - s*cT;
  __shared__ float lx[cK][cNS], ly[cK][cNS];
  int tid = threadIdx.x;
  for (int p = tid; p < cK*cNS; p += 256){
    int k = p >> 5, i = p & 31;
    int row = t*cKN + k*cN + s*cNS + i;
    lx[k][i] = locsc[row*2+0];
    ly[k][i] = locsc[row*2+1];
  }
  __syncthreads();
  for (int p = tid; p < 1024; p += 256){
    int i = p >> 5, j = p & 31;
    bool any = false;
    for (int k = 0; k < cK; ++k){
      float dx = fabsf(lx[k][i]-lx[k][j]);
      float dy = fabsf(ly[k][i]-ly[k][j]);
      any = any || ((dx < 10.f) && (dy < 10.f));
    }
    m[st*1024 + p] = any ? 1 : 0;
  }
}

// QKV projection, 16 rows/block, weight reuse for 8 rows/thread
__global__ __launch_bounds__(256) void k_qkv(const float* x,
  const float* Wq, const float* bq, const float* Wk, const float* bk,
  const float* Wv, const float* bv,
  float* Q, float* K2, float* V){
  const int ROWS = 16;
  int r0 = blockIdx.x*ROWS;
  __shared__ float xs[ROWS][cH];
  int tid = threadIdx.x;
  for (int p = tid; p < ROWS*32; p += 256){
    int rr = p>>5, u4 = p&31;
    ((float4*)&xs[rr][0])[u4] = ((const float4*)x)[(size_t)(r0+rr)*32 + u4];
  }
  __syncthreads();
  int cl = tid & 127, half = tid >> 7;
  float aq[8], ak[8], av[8];
  float bq0 = bq[cl], bk0 = bk[cl], bv0 = bv[cl];
  #pragma unroll
  for (int r = 0; r < 8; ++r){ aq[r] = bq0; ak[r] = bk0; av[r] = bv0; }
  for (int i = 0; i < cH; ++i){
    float wq = Wq[i*cH+cl], wk = Wk[i*cH+cl], wv = Wv[i*cH+cl];
    #pragma unroll
    for (int q2 = 0; q2 < 8; ++q2){
      float xi = xs[half + 2*q2][i];
      aq[q2] += xi*wq; ak[q2] += xi*wk; av[q2] += xi*wv;
    }
  }
  #pragma unroll
  for (int q2 = 0; q2 < 8; ++q2){
    size_t gi = (size_t)(r0 + half + 2*q2)*cH + cl;
    Q[gi] = aq[q2]; K2[gi] = ak[q2]; V[gi] = av[q2];
  }
}

// flash-style masked MHSA (round-6 16-row version): online softmax,
// double-buffered K/V with register prefetch, 2 barriers per 64-key tile.
__global__ __launch_bounds__(256) void k_attn(const float* Q, const float* Kx, const float* V,
                       const unsigned char* msk, float* ctx){
  int tile = blockIdx.x;        // 0..39 (16 q-rows each)
  int head = blockIdx.y;        // 0..3
  int st   = blockIdx.z;        // s*cT + t
  int s = st / cT, t = st - s*cT;
  __shared__ float Kb[2][64][36];        // 18432 B
  __shared__ float Vb[2][32][68];        // 17408 B (V transposed per tile)
  __shared__ float Pb[16][68];           // 4352 B
  __shared__ unsigned char ml[1024];
  int tid = threadIdx.x;
  int qr = tid >> 4, ks = tid & 15;
  int l0 = tile*16;
  for (int p = tid; p < 1024; p += 256) ml[p] = msk[st*1024 + p];
  float4 qreg[8];
  {
    int l = l0 + qr;
    int grow = t*cKN + (l>>5)*cN + s*cNS + (l&31);
    const float4* qp = (const float4*)Q + (size_t)grow*32 + head*8;
    #pragma unroll
    for (int m = 0; m < 8; ++m) qreg[m] = qp[m];
  }
  int iq = (l0 + qr) & 31;
  int kk_a = tid >> 3,          f4_a = tid & 7;
  int kk_b = (tid+256) >> 3,    f4_b = tid & 7;
  const float scl = 0.17677669529663687f;   // 1/sqrt(32)

  #define KADDR(c0,kk,f4) ((const float4*)Kx + (size_t)(t*cKN + (((c0)+(kk))>>5)*cN + s*cNS + (((c0)+(kk))&31))*32 + head*8 + (f4))
  #define VADDR(c0,kk,f4) ((const float4*)V  + (size_t)(t*cKN + (((c0)+(kk))>>5)*cN + s*cNS + (((c0)+(kk))&31))*32 + head*8 + (f4))

  float4 kpre0 = *KADDR(0, kk_a, f4_a);
  float4 kpre1 = *KADDR(0, kk_b, f4_b);
  float4 vpre0 = *VADDR(0, kk_a, f4_a);
  float4 vpre1 = *VADDR(0, kk_b, f4_b);
  {
    ((float4*)&Kb[0][kk_a][0])[f4_a] = kpre0;
    ((float4*)&Kb[0][kk_b][0])[f4_b] = kpre1;
    int d0 = f4_a*4;
    Vb[0][d0+0][kk_a] = vpre0.x; Vb[0][d0+1][kk_a] = vpre0.y;
    Vb[0][d0+2][kk_a] = vpre0.z; Vb[0][d0+3][kk_a] = vpre0.w;
    Vb[0][d0+0][kk_b] = vpre1.x; Vb[0][d0+1][kk_b] = vpre1.y;
    Vb[0][d0+2][kk_b] = vpre1.z; Vb[0][d0+3][kk_b] = vpre1.w;
  }
  __syncthreads();

  float m_run = -3.4e38f, l_run = 0.f, O0 = 0.f, O1 = 0.f;
  unsigned char mb0 = ml[iq*32 + ks];
  unsigned char mb1 = ml[iq*32 + ks + 16];

  for (int c = 0; c < 10; ++c){
    int par = c & 1;
    if (c < 9){
      int c1 = (c+1)*64;
      kpre0 = *KADDR(c1, kk_a, f4_a);
      kpre1 = *KADDR(c1, kk_b, f4_b);
      vpre0 = *VADDR(c1, kk_a, f4_a);
      vpre1 = *VADDR(c1, kk_b, f4_b);
    }
    float sc[4];
    #pragma unroll
    for (int kk2 = 0; kk2 < 4; ++kk2){
      int key = ks + 16*kk2;
      const float4* kr = (const float4*)&Kb[par][key][0];
      float acc = 0.f;
      #pragma unroll
      for (int m = 0; m < 8; ++m){
        float4 kv = kr[m];
        acc += qreg[m].x*kv.x + qreg[m].y*kv.y + qreg[m].z*kv.z + qreg[m].w*kv.w;
      }
      sc[kk2] = acc*scl;
    }
    float s0 = mb0 ? sc[0] : -3.4e38f;
    float s1 = mb1 ? sc[1] : -3.4e38f;
    float s2 = mb0 ? sc[2] : -3.4e38f;
    float s3 = mb1 ? sc[3] : -3.4e38f;
    float tmax = fmaxf(fmaxf(s0,s1), fmaxf(s2,s3));
    #pragma unroll
    for (int off = 1; off < 16; off <<= 1)
      tmax = fmaxf(tmax, __shfl_xor(tmax, off, 16));
    float m_new = fmaxf(m_run, tmax);
    float alpha = expf(m_run - m_new);
    float p0 = mb0 ? expf(s0 - m_new) : 0.f;
    float p1 = mb1 ? expf(s1 - m_new) : 0.f;
    float p2 = mb0 ? expf(s2 - m_new) : 0.f;
    float p3 = mb1 ? expf(s3 - m_new) : 0.f;
    float psum = p0+p1+p2+p3;
    #pragma unroll
    for (int off = 1; off < 16; off <<= 1)
      psum += __shfl_xor(psum, off, 16);
    l_run = l_run*alpha + psum;
    m_run = m_new;
    Pb[qr][ks] = p0; Pb[qr][ks+16] = p1; Pb[qr][ks+32] = p2; Pb[qr][ks+48] = p3;
    __syncthreads();   // Pb visible to all lanes of the qr group
    O0 *= alpha; O1 *= alpha;
    const float4* pr = (const float4*)&Pb[qr][0];
    const float4* v0 = (const float4*)&Vb[par][ks][0];
    const float4* v1 = (const float4*)&Vb[par][ks+16][0];
    #pragma unroll
    for (int m = 0; m < 16; ++m){
      float4 pv = pr[m];
      float4 a = v0[m];
      float4 b = v1[m];
      O0 += pv.x*a.x + pv.y*a.y + pv.z*a.z + pv.w*a.w;
      O1 += pv.x*b.x + pv.y*b.y + pv.z*b.z + pv.w*b.w;
    }
    if (c < 9){
      int nb = 1 - par;
      ((float4*)&Kb[nb][kk_a][0])[f4_a] = kpre0;
      ((float4*)&Kb[nb][kk_b][0])[f4_b] = kpre1;
      int d0 = f4_a*4;
      Vb[nb][d0+0][kk_a] = vpre0.x; Vb[nb][d0+1][kk_a] = vpre0.y;
      Vb[nb][d0+2][kk_a] = vpre0.z; Vb[nb][d0+3][kk_a] = vpre0.w;
      Vb[nb][d0+0][kk_b] = vpre1.x; Vb[nb][d0+1][kk_b] = vpre1.y;
      Vb[nb][d0+2][kk_b] = vpre1.z; Vb[nb][d0+3][kk_b] = vpre1.w;
    }
    __syncthreads();   // buffer swap + Pb reads done before next-tile Pb write
  }
  #undef KADDR
  #undef VADDR
  {
    float rinv = 1.f / l_run;
    int l = l0 + qr;
    int grow = t*cKN + (l>>5)*cN + s*cNS + (l&31);
    ctx[(size_t)grow*cH + head*cHD + ks]      = O0 * rinv;
    ctx[(size_t)grow*cH + head*cHD + ks + 16] = O1 * rinv;
  }
}

// Wo1 + relu, 8 rows/block, weight reuse
__global__ __launch_bounds__(256) void k_wo1(const float* x, const float* W, const float* b, float* o){
  const int ROWS = 8;
  int r0 = blockIdx.x*ROWS;
  __shared__ float xs[ROWS][cH];
  int tid = threadIdx.x;
  {
    int rr = tid>>5, u4 = tid&31;
    ((float4*)&xs[rr][0])[u4] = ((const float4*)x)[(size_t)(r0+rr)*32 + u4];
  }
  __syncthreads();
  float a[8];
  float bb = b[tid];
  #pragma unroll
  for (int r = 0; r < 8; ++r) a[r] = bb;
  for (int i = 0; i < cH; ++i){
    float w = W[i*256 + tid];
    #pragma unroll
    for (int r = 0; r < 8; ++r) a[r] += xs[r][i]*w;
  }
  #pragma unroll
  for (int r = 0; r < 8; ++r) o[(size_t)(r0+r)*256 + tid] = fmaxf(a[r], 0.f);
}

// Wo2, 16 rows/block, weight reuse
__global__ __launch_bounds__(256) void k_wo2(const float* x, const float* W, const float* b, float* o){
  const int ROWS = 16;
  int r0 = blockIdx.x*ROWS;
  __shared__ float xs[ROWS][256];
  int tid = threadIdx.x;
  for (int p = tid; p < ROWS*64; p += 256){
    int rr = p>>6, u4 = p&63;
    ((float4*)&xs[rr][0])[u4] = ((const float4*)x)[(size_t)(r0+rr)*64 + u4];
  }
  __syncthreads();
  int cl = tid & 127, half = tid >> 7;
  float a[8];
  float bb = b[cl];
  #pragma unroll
  for (int r = 0; r < 8; ++r) a[r] = bb;
  for (int i = 0; i < 256; ++i){
    float w = W[i*cH + cl];
    #pragma unroll
    for (int q2 = 0; q2 < 8; ++q2) a[q2] += xs[half + 2*q2][i]*w;
  }
  #pragma unroll
  for (int q2 = 0; q2 < 8; ++q2) o[(size_t)(r0 + half + 2*q2)*cH + cl] = a[q2];
}

extern "C" void kernel_launch(void* const* d_in, const int* in_sizes, int n_in,
                              void* d_out, int out_size, void* d_ws, size_t ws_size,
                              hipStream_t stream){
  (void)in_sizes; (void)n_in; (void)out_size; (void)ws_size;

  int*   flagp = (int*)d_ws;
  float* conv  = (float*)d_ws + 64;
  float* big   = (float*)d_ws + 978112;

  const float* ge_f   = conv + 0;
  const float* hs_f   = conv + 196608;
  const float* cn_f   = conv + 212992;
  const float* sv_f   = conv + 229376;
  const float* mx_f   = conv + 229632;
  const float* mhpW_f = conv + 229888;
  const float* mhpb_f = conv + 557568;
  const float* mhpg_f = conv + 560128;
  const float* mhpbe_f= conv + 562688;
  const float* l1Wih_f= conv + 565248;
  const float* l1Whh_f= conv + 630784;
  const float* l1b_f  = conv + 696320;
  const float* l2Wih_f= conv + 696832;
  const float* l2Whh_f= conv + 762368;
  const float* l2b_f  = conv + 827904;
  const float* Wq_f   = conv + 828416;
  const float* bq_f   = conv + 844800;
  const float* Wk_f   = conv + 844928;
  const float* bk_f   = conv + 861312;
  const float* Wv_f   = conv + 861440;
  const float* bv_f   = conv + 877824;
  const float* Wo1_f  = conv + 877952;
  const float* bo1_f  = conv + 910720;
  const float* Wo2_f  = conv + 910976;
  const float* bo2_f  = conv + 943744;
  const float* locW1_f= conv + 943872;
  const float* locb1_f= conv + 960256;
  const float* locg_f = conv + 960384;
  const float* locbe_f= conv + 960512;
  const float* locW2_f= conv + 960640;
  const float* locb2_f= conv + 960896;
  const float* sclW1_f= conv + 960960;
  const float* sclb1_f= conv + 977344;
  const float* sclg_f = conv + 977472;
  const float* sclbe_f= conv + 977600;
  const float* sclW2_f= conv + 977728;
  const float* sclb2_f= conv + 977984;

  const size_t SLOT = (size_t)cT*cKN*cH;
  float* geb = big;
  float* o1b = big + SLOT;
  float* Qb  = big + 2*SLOT;
  float* Kb  = big + 3*SLOT;
  float* Vb  = big + 4*SLOT;
  float* locsc = big + 5*SLOT;
  unsigned char* maskb = (unsigned char*)(locsc + (size_t)cT*cKN*2);
  float* t1 = Qb;        // spans slots 2-3 (Q/K dead after attn)
  float* social = Vb;    // overlays V after attention

  Ptrs ptrs;
  for (int i = 0; i < 37; ++i) ptrs.p[i] = d_in[i];

  k_detect<<<1, 64, 0, stream>>>((const unsigned short*)d_in[0], flagp, (unsigned int*)d_out);
  k_convert<<<(CONV_TOTAL+255)/256, 256, 0, stream>>>(ptrs, flagp, conv);
  k_mhp<<<cT*cN/2, 256, 0, stream>>>(ge_f, mhpW_f, mhpb_f, mhpg_f, mhpbe_f, geb);
  k_lstm_seq<<<cKN/8, 256, 0, stream>>>(geb, o1b, hs_f, cn_f, (const float*)0,
                                        l1Wih_f, l1Whh_f, l1b_f, 1);
  k_heads<<<cT*cKN/4, 256, 0, stream>>>(o1b, locW1_f,locb1_f,locg_f,locbe_f,locW2_f,locb2_f,
                                        sclW1_f,sclb1_f,sclg_f,sclbe_f,sclW2_f,sclb2_f,
                                        d_out, 0, locsc, mx_f, sv_f, flagp);
  k_mask<<<cS*cT, 256, 0, stream>>>(locsc, maskb);
  k_qkv<<<cT*cKN/16, 256, 0, stream>>>(o1b, Wq_f,bq_f, Wk_f,bk_f, Wv_f,bv_f, Qb, Kb, Vb);
  {
    dim3 ag(cL/16, 4, cS*cT);
    k_attn<<<ag, 256, 0, stream>>>(Qb, Kb, Vb, maskb, o1b);   // ctx overlays out1
  }
  k_wo1<<<cT*cKN/8, 256, 0, stream>>>(o1b, Wo1_f, bo1_f, t1);
  k_wo2<<<cT*cKN/16, 256, 0, stream>>>(t1, Wo2_f, bo2_f, social);
  k_lstm_seq<<<cKN/8, 256, 0, stream>>>(geb, o1b, hs_f, cn_f, social,
                                        l2Wih_f, l2Whh_f, l2b_f, 2);
  k_heads<<<cT*cKN/4, 256, 0, stream>>>(o1b, locW1_f,locb1_f,locg_f,locbe_f,locW2_f,locb2_f,
                                        sclW1_f,sclb1_f,sclg_f,sclbe_f,sclW2_f,sclb2_f,
                                        d_out, 2, (float*)0, mx_f, sv_f, flagp);
}